// Round 10
// baseline (6798.176 us; speedup 1.0000x reference)
//
#include <hip/hip_runtime.h>
#include <cstddef>
#include <math.h>

// Problem: B=64, S=1024, F=128, H=512, V=64, T=64. f32 in/out.
// R16 = pair-multiplexed R14: hide the exchange chain under the other chain.
//  - Evidence: R14 (volume/2: -6%), R15 (fanout/2: regress) -> the ~3.4us
//    exposed serial chain (store-ack, flag-vis, detect, stage RT; ~2000cyc
//    trips) is the floor, not bandwidth. R10's multiplex failed because its
//    fire-and-forget store was drained by the NEXT sub-step's vmcnt(0)
//    (FIFO) - schedule bug, not concept refutation.
//  - Design: 8 groups x 8 batches; 128 WGs; each WG serves TWO groups with
//    the SAME dim slice p (16 dims/gate) -> same register weights (no R15
//    VGPR blowup). Iteration = phase A (group A, step t) + phase B (group B,
//    step t). Each phase's chain hides under the other phase's compute; each
//    phase's h-store ack is drained by the OTHER phase's STAGE VMWAIT (needed
//    anyway) and the flag rides free right after it.
//  - Flags: one monotone counter/WG/pair-set (32 slots): 2t+... encoder:
//    fl=2t (my hB(t) acked, set in STAGE_A of iter t), fl=2t+1 (my hA(t+1)
//    acked, set in STAGE_B). waitA(t)=2t-1, waitB(t)=2t. Overwrite-safety:
//    stage of h(t-1) precedes flag that gates h(t+1) store (2-deep dbuf).
//  - A-frag rows: 8 real batches duplicated to rows 8-15 (rmn=mn&7); C rows
//    8-15 discarded (GWRITE q<2). All exchange on the proven sc0|sc1 path.
#define NWG 128
#define BPG 8
#define HH  512
#define TT  64
#define VV  64
#define FF  128
#define SS  1024

typedef _Float16 f16;
typedef _Float16 f16x8 __attribute__((ext_vector_type(8)));
typedef float    f32x4 __attribute__((ext_vector_type(4)));
typedef unsigned int u32;
typedef unsigned short u16;
typedef u32 u32x4 __attribute__((ext_vector_type(4)));
typedef unsigned long long u64;

#define C1 4.8828125e-4f          // 2^-11
#define C2 2.384185791015625e-7f  // 2^-22

__device__ __forceinline__ void split8(const float* __restrict__ p, f16x8& hi, f16x8& lo) {
  f32x4 u = *(const f32x4*)p;
  f32x4 v = *(const f32x4*)(p + 4);
#pragma unroll
  for (int j = 0; j < 4; ++j) {
    f16 a = (f16)u[j]; hi[j]   = a; lo[j]   = (f16)((u[j] - (float)a) * 2048.0f);
    f16 b = (f16)v[j]; hi[4+j] = b; lo[4+j] = (f16)((v[j] - (float)b) * 2048.0f);
  }
}
__device__ __forceinline__ float sigmf_(float x) { return 1.0f / (1.0f + expf(-x)); }

// far (coherence-point) accessors — R8/R13/R14-proven pattern
__device__ __forceinline__ f32x4 ld16f(const void* p) {
  f32x4 r;
  asm volatile("global_load_dwordx4 %0, %1, off sc0 sc1" : "=v"(r) : "v"(p) : "memory");
  return r;
}
__device__ __forceinline__ void st4f(u32* p, u32 v) {
  __hip_atomic_store(p, v, __ATOMIC_RELAXED, __HIP_MEMORY_SCOPE_AGENT);
}
__device__ __forceinline__ void st4ff(float* p, float v) {
  __hip_atomic_store(p, v, __ATOMIC_RELAXED, __HIP_MEMORY_SCOPE_AGENT);
}
__device__ __forceinline__ u32 ld4f(const u32* p) {
  return __hip_atomic_load(p, __ATOMIC_RELAXED, __HIP_MEMORY_SCOPE_AGENT);
}
#define VMWAIT asm volatile("s_waitcnt vmcnt(0)" ::: "memory")

// barrier: poll this pair-set's 32 per-WG flags with one 64-lane gather
__device__ __forceinline__ void wait_flags(const u32* flags, u32 target, int lane) {
  const u32* a = flags + (size_t)(lane & 31) * 32;   // 128B stride
  while (!__all(ld4f(a) >= target))
    __builtin_amdgcn_s_sleep(1);
}

#define MFMA(d, a, b) d = __builtin_amdgcn_mfma_f32_16x16x32_f16(a, b, d, 0, 0, 0)

// one-shot h stage: group tile [8][256] u32 (f16 dim pairs) -> LDS f16.
// Thread: row r=tid>>5, u32 cols (tid&31)*8..+7. Per load instruction: 32
// same-row lanes contiguous 1KB (coalesced). LDS: two 16B writes at
// (r*1024 + (tid&31)*32 (+16)) ^ (r<<4); rows 0/1 (one wave) interleave
// complementary 16B halves across all 32 banks -> conflict-free optimal.
// rule #18: tie values through volatile asm + sched_barrier after VMWAIT.
#define STAGE_H2(src_, SH)                                                    \
  { const u32* src = (src_) + (size_t)(tid >> 5) * 256 + (size_t)(tid & 31) * 8; \
    f32x4 sv0 = ld16f(src), sv1 = ld16f(src + 4);                             \
    VMWAIT;                                                                   \
    asm volatile("" : "+v"(sv0), "+v"(sv1));                                  \
    __builtin_amdgcn_sched_barrier(0);                                        \
    const int r_ = tid >> 5;                                                  \
    const size_t base_ = (size_t)r_ * 1024 + (size_t)(tid & 31) * 32;         \
    const size_t swz_ = (size_t)(r_ << 4);                                    \
    *(u32x4*)((char*)(SH) + (base_ ^ swz_))        = __builtin_bit_cast(u32x4, sv0); \
    *(u32x4*)((char*)(SH) + ((base_ + 16) ^ swz_)) = __builtin_bit_cast(u32x4, sv1); \
  }

// A-fragment read (row = batch rmn (8 real), k-slice s), same swizzle
#define LDA2(SH, s, ah)                                                       \
  { size_t o_ = ((size_t)rmn * 1024 + (size_t)(s) * 64 + (size_t)(q8 * 2))    \
                ^ (size_t)(rmn << 4);                                         \
    ah = *(const f16x8*)((const char*)(SH) + o_); }

// h-part: h f16-only; W hi+lo
#define HPART2(SH, A0, A1)                                                    \
  _Pragma("unroll") for (int s = 0; s < 16; ++s) {                            \
    f16x8 ah; LDA2(SH, s, ah);                                                \
    MFMA(A0, ah, whh_h[s]);                                                   \
    MFMA(A1, ah, whh_l[s]);                                                   \
  }

// x-part for group base gbX, sig row ts (full Ootomo); re-inits accs
#define XPART2(gbX, ts, A0, A1, A2)                                           \
  { A0 = zero4; A1 = zero4; A2 = zero4;                                       \
    const float* sb = sig + (size_t)((gbX) + rmn) * (SS * FF) + (size_t)(ts) * FF; \
    _Pragma("unroll") for (int s = 0; s < 4; ++s) {                           \
      f16x8 xh, xl;                                                           \
      split8(sb + s * 32 + q8, xh, xl);                                       \
      MFMA(A0, xh, wih_h[s]);                                                 \
      MFMA(A1, xl, wih_h[s]);                                                 \
      MFMA(A1, xh, wih_l[s]);                                                 \
      MFMA(A2, xl, wih_l[s]);                                                 \
    } }

// C/D: col = mn = h-dim, row = q*4+r = batch; keep rows 0-7 (q<2)
#define GWRITE2(A0, A1, A2)                                                   \
  if (q < 2)                                                                  \
    _Pragma("unroll") for (int r = 0; r < 4; ++r)                             \
      gate_buf[w][q * 4 + r][mn] = A0[r] + C1 * A1[r] + C2 * A2[r];

// pack h f16 pair across (even,odd) lanes via shfl; even tids store u32.
#define HSTORE2(dst, h)                                                       \
  { u32 mine = (u32)__builtin_bit_cast(u16, (f16)(h));                        \
    u32 part = (u32)__shfl_xor((int)mine, 1, 64);                             \
    if ((tid & 1) == 0)                                                       \
      st4f((dst) + (size_t)cb * 256 + p * 8 + (ck >> 1), mine | (part << 16)); }

__global__ void __launch_bounds__(256, 1) lstm_seq2seq(
    const float* __restrict__ sig,   // [B,S,F]
    const int*   __restrict__ tgt,   // [B,T]
    const float* __restrict__ eWih,  // [2048,128]
    const float* __restrict__ eWhh,  // [2048,512]
    const float* __restrict__ eBih,  // [2048]
    const float* __restrict__ eBhh,  // [2048]
    const float* __restrict__ dWih,  // [2048,64]
    const float* __restrict__ dWhh,  // [2048,512]
    const float* __restrict__ dBih,  // [2048]
    const float* __restrict__ dBhh,  // [2048]
    const float* __restrict__ oW,    // [64,512]
    const float* __restrict__ oB,    // [64]
    float*       __restrict__ out,   // [B,T,V]
    unsigned char* __restrict__ ws)
{
  // ws layout (bytes): [0,16384) flags 4 pair-sets x 32 slots x 128B;
  // [16384,16640) idxbuf u32[64]; [20480,151552) h16 8 groups x 2 buf x 8KB
  // u32 {f16 2j | f16 2j+1 <<16}; [151552,282624) hfg 8 groups x 8 x 512 f32.
  // Zeroed region = [0,151552) every launch (ws re-poisoned 0xAA); packed 0
  // = h0 = zeros. hfg fully written before read (flag-guarded).
  const int wg   = blockIdx.x;
  const int pair = wg >> 5;          // pair-set 0..3 -> groups 2pair, 2pair+1
  const int p    = wg & 31;          // dim slice [p*16, p*16+16) per gate
  const int gA   = 2 * pair, gB = 2 * pair + 1;
  const int gbA  = gA * BPG, gbB = gB * BPG;
  u32* fl     = (u32*)ws + (size_t)pair * 1024;
  u32* idxbuf = (u32*)(ws + 16384);
  u32* h16A[2] = { (u32*)(ws + 20480) + (size_t)(gA*2 + 0) * 2048,
                   (u32*)(ws + 20480) + (size_t)(gA*2 + 1) * 2048 };
  u32* h16B[2] = { (u32*)(ws + 20480) + (size_t)(gB*2 + 0) * 2048,
                   (u32*)(ws + 20480) + (size_t)(gB*2 + 1) * 2048 };
  float* hfgA = (float*)(ws + 151552) + (size_t)gA * 4096;
  float* hfgB = (float*)(ws + 151552) + (size_t)gB * 4096;

  const int tid  = threadIdx.x;
  const int w    = tid >> 6;         // wave = gate (i,f,g,o)
  const int lane = tid & 63;
  const int q    = lane >> 4;
  const int mn   = lane & 15;
  const int rmn  = mn & 7;           // batch row (8 real; 8-15 duplicate)
  const int q8   = q * 8;
  const int row  = w * HH + p * 16 + mn;  // weight row for this lane's B-frag
  const int cb   = tid >> 4;         // cell: local batch (tid<128 -> 0..7)
  const int ck   = tid & 15;         // cell: dim within slice
  const int crow = p * 16 + ck;      // cell: h-dim

  __shared__ __attribute__((aligned(16))) f16 sh_A[8 * 512];  // 8KB swizzled
  __shared__ __attribute__((aligned(16))) f16 sh_B[8 * 512];
  __shared__ float gate_buf[4][8][17];
  __shared__ float bias_buf[4][16];
  __shared__ __attribute__((aligned(16))) float hrow[512];
  __shared__ double psum[64];

  // ---- weights: W_hh and W_ih hi/lo fragments in registers (shared by both
  // chains — same dim slice) ----
  f16x8 whh_h[16], whh_l[16], wih_h[4], wih_l[4];
#pragma unroll
  for (int s = 0; s < 16; ++s)
    split8(eWhh + (size_t)row * HH + s * 32 + q8, whh_h[s], whh_l[s]);
#pragma unroll
  for (int s = 0; s < 4; ++s)
    split8(eWih + (size_t)row * FF + s * 32 + q8, wih_h[s], wih_l[s]);
  if (tid < 64) {
    int g4 = tid >> 4, kl = tid & 15;
    int r = g4 * HH + p * 16 + kl;
    bias_buf[g4][kl] = eBih[r] + eBhh[r];
  }
  if (p == 0 && tid < 16)            // initial idx = target[:,0]
    st4f(idxbuf + pair * 16 + tid, (u32)tgt[(size_t)(pair * 16 + tid) * TT]);
  __syncthreads();

  float c_regA = 0.f, c_regB = 0.f;
  const f32x4 zero4 = {0.f, 0.f, 0.f, 0.f};
  f32x4 accA0, accA1, accA2, accB0, accB1, accB2;

  // ================= encoder: 1024 iters x 2 phases =================
  XPART2(gbA, 0, accA0, accA1, accA2)
  for (int t = 0; t < SS; ++t) {
    const int pb = t & 1;
    // ---- phase A (group gA, step t) ----
    if (t) wait_flags(fl, (u32)(2*t - 1), lane);   // others' hA(t) acked
    STAGE_H2(h16A[pb], sh_A)
    if (t && tid == 0) st4f(fl + p * 32, (u32)(2*t));  // my hB(t) acked
    __syncthreads();
    HPART2(sh_A, accA0, accA1)
    GWRITE2(accA0, accA1, accA2)
    __syncthreads();
    if (tid < 128) {                 // cell A: 1 h/thread, store h16
      float gi = gate_buf[0][cb][ck] + bias_buf[0][ck];
      float gf = gate_buf[1][cb][ck] + bias_buf[1][ck];
      float gg = gate_buf[2][cb][ck] + bias_buf[2][ck];
      float go = gate_buf[3][cb][ck] + bias_buf[3][ck];
      float c  = sigmf_(gf) * c_regA + sigmf_(gi) * tanhf(gg);
      float h  = sigmf_(go) * tanhf(c);
      c_regA = c;
      HSTORE2(h16A[pb ^ 1], h)
    }
    XPART2(gbB, t, accB0, accB1, accB2)            // hides A-store latency
    // ---- phase B (group gB, step t) ----
    wait_flags(fl, (u32)(2*t), lane);              // others' hB(t) acked
    STAGE_H2(h16B[pb], sh_B)
    if (tid == 0) st4f(fl + p * 32, (u32)(2*t + 1)); // my hA(t+1) acked
    __syncthreads();
    HPART2(sh_B, accB0, accB1)
    GWRITE2(accB0, accB1, accB2)
    __syncthreads();
    if (tid < 128) {                 // cell B
      float gi = gate_buf[0][cb][ck] + bias_buf[0][ck];
      float gf = gate_buf[1][cb][ck] + bias_buf[1][ck];
      float gg = gate_buf[2][cb][ck] + bias_buf[2][ck];
      float go = gate_buf[3][cb][ck] + bias_buf[3][ck];
      float c  = sigmf_(gf) * c_regB + sigmf_(gi) * tanhf(gg);
      float h  = sigmf_(go) * tanhf(c);
      c_regB = c;
      HSTORE2(h16B[pb ^ 1], h)
    }
    XPART2(gbA, t + 1 < SS ? t + 1 : SS - 1, accA0, accA1, accA2) // hides B-store
  }

  // ================= decoder setup =================
#pragma unroll
  for (int s = 0; s < 16; ++s)
    split8(dWhh + (size_t)row * HH + s * 32 + q8, whh_h[s], whh_l[s]);
  __syncthreads();
  if (tid < 64) {
    int g4 = tid >> 4, kl = tid & 15;
    int r = g4 * HH + p * 16 + kl;
    bias_buf[g4][kl] = dBih[r] + dBhh[r];
  }
  __syncthreads();

  // ================= decoder: 64 iters =================
  // flags: base = 2*SS + 4t; +1 my hB(SS+t) acked (STAGE_A); +2 my hA(SS+t+1)
  // + hfgA acked (STAGE_B); +3 my hB(SS+t+1) + hfgB acked (explicit VMWAIT);
  // +4 logits done (idx(t+1) acked).
  for (int t = 0; t < TT; ++t) {
    const int pb = (SS + t) & 1;
    const u32 base = (u32)(2 * SS + 4 * t);
    // ---- phase A (cell for group gA) ----
    wait_flags(fl, t ? base : (u32)(2 * SS - 1), lane);
    STAGE_H2(h16A[pb], sh_A)
    if (tid == 0) st4f(fl + p * 32, base + 1);
    __syncthreads();
    accA0 = zero4; accA1 = zero4; accA2 = zero4;
    HPART2(sh_A, accA0, accA1)
    GWRITE2(accA0, accA1, accA2)
    __syncthreads();
    if (tid < 128) {
      int ib = (int)ld4f(idxbuf + gbA + cb);
      float gi = gate_buf[0][cb][ck] + bias_buf[0][ck] + dWih[(size_t)(0*HH + crow) * VV + ib];
      float gf = gate_buf[1][cb][ck] + bias_buf[1][ck] + dWih[(size_t)(1*HH + crow) * VV + ib];
      float gg = gate_buf[2][cb][ck] + bias_buf[2][ck] + dWih[(size_t)(2*HH + crow) * VV + ib];
      float go = gate_buf[3][cb][ck] + bias_buf[3][ck] + dWih[(size_t)(3*HH + crow) * VV + ib];
      float c  = sigmf_(gf) * c_regA + sigmf_(gi) * tanhf(gg);
      float h  = sigmf_(go) * tanhf(c);
      c_regA = c;
      HSTORE2(h16A[pb ^ 1], h)
      st4ff(hfgA + (size_t)cb * HH + crow, h);
    }
    // ---- phase B (cell for group gB) ----
    wait_flags(fl, base + 1, lane);
    STAGE_H2(h16B[pb], sh_B)
    if (tid == 0) st4f(fl + p * 32, base + 2);
    __syncthreads();
    accB0 = zero4; accB1 = zero4; accB2 = zero4;
    HPART2(sh_B, accB0, accB1)
    GWRITE2(accB0, accB1, accB2)
    __syncthreads();
    if (tid < 128) {
      int ib = (int)ld4f(idxbuf + gbB + cb);
      float gi = gate_buf[0][cb][ck] + bias_buf[0][ck] + dWih[(size_t)(0*HH + crow) * VV + ib];
      float gf = gate_buf[1][cb][ck] + bias_buf[1][ck] + dWih[(size_t)(1*HH + crow) * VV + ib];
      float gg = gate_buf[2][cb][ck] + bias_buf[2][ck] + dWih[(size_t)(2*HH + crow) * VV + ib];
      float go = gate_buf[3][cb][ck] + bias_buf[3][ck] + dWih[(size_t)(3*HH + crow) * VV + ib];
      float c  = sigmf_(gf) * c_regB + sigmf_(gi) * tanhf(gg);
      float h  = sigmf_(go) * tanhf(c);
      c_regB = c;
      HSTORE2(h16B[pb ^ 1], h)
      st4ff(hfgB + (size_t)cb * HH + crow, h);
    }
    VMWAIT;                          // drain hB + hfgB stores (exposed, 64x)
    __syncthreads();
    if (tid == 0) st4f(fl + p * 32, base + 3);
    // ---- logits: WG p<16 -> batch pair*16+p ----
    wait_flags(fl, base + 3, lane);  // all hfg rows acked
    if (p < 16) {
      const float* hsrc = ((p >> 3) ? hfgB : hfgA) + (size_t)(p & 7) * HH;
      if (tid < 128) {
        f32x4 hv = ld16f(hsrc + (size_t)tid * 4);
        VMWAIT;
        *(f32x4*)&hrow[tid * 4] = hv;
      }
      __syncthreads();
      double acc = 0.0;
      if (w < 2) {                   // waves 0,1 split K=512 in halves
        const float* wr = oW + (size_t)lane * HH + w * 256;
        const float* hr = hrow + w * 256;
#pragma unroll 4
        for (int kc = 0; kc < 64; ++kc) {
          f32x4 hv = *(const f32x4*)(hr + kc * 4);
          f32x4 wv = *(const f32x4*)(wr + kc * 4);
          acc += (double)hv[0]*(double)wv[0] + (double)hv[1]*(double)wv[1]
               + (double)hv[2]*(double)wv[2] + (double)hv[3]*(double)wv[3];
        }
        if (w == 1) psum[lane] = acc;
      }
      __syncthreads();
      if (w == 0) {
        double l = acc + psum[lane] + (double)oB[lane];
        double mx = l; int ai = lane;
#pragma unroll
        for (int o = 32; o > 0; o >>= 1) {
          double om = __shfl_xor(mx, o, 64);
          int    oi = __shfl_xor(ai, o, 64);
          if (om > mx || (om == mx && oi < ai)) { mx = om; ai = oi; }
        }
        double se = exp(l - mx);
#pragma unroll
        for (int o = 32; o > 0; o >>= 1) se += __shfl_xor(se, o, 64);
        double lse = mx + log(se);
        out[((size_t)(pair * 16 + p) * TT + t) * VV + lane] = (float)(l - lse);
        if (lane == 0) st4f(idxbuf + pair * 16 + p, (u32)ai);
      }
    }
    VMWAIT;                          // idx store acked
    __syncthreads();                 // hrow/psum/gate_buf reuse fence
    if (tid == 0) st4f(fl + p * 32, base + 4);
  }
}

extern "C" void kernel_launch(void* const* d_in, const int* in_sizes, int n_in,
                              void* d_out, int out_size, void* d_ws, size_t ws_size,
                              hipStream_t stream) {
  (void)in_sizes; (void)n_in; (void)out_size; (void)ws_size;
  // zero: flags + idxbuf + h16 dbufs (ws re-poisoned 0xAA before every timed
  // launch -> must zero every call). hfg fully written before read.
  hipMemsetAsync(d_ws, 0, 151552, stream);
  lstm_seq2seq<<<dim3(NWG), dim3(256), 0, stream>>>(
      (const float*)d_in[0],  (const int*)d_in[1],
      (const float*)d_in[2],  (const float*)d_in[3],
      (const float*)d_in[4],  (const float*)d_in[5],
      (const float*)d_in[6],  (const float*)d_in[7],
      (const float*)d_in[8],  (const float*)d_in[9],
      (const float*)d_in[10], (const float*)d_in[11],
      (float*)d_out, (unsigned char*)d_ws);
}

// Round 11
// 5927.234 us; speedup vs baseline: 1.1469x; 1.1469x over previous
//
#include <hip/hip_runtime.h>
#include <cstddef>
#include <math.h>

// Problem: B=64, S=1024, F=128, H=512, V=64, T=64. f32 in/out.
// R17 = R14 (proven 5015us, absmax 0.031) + single-counter barrier:
//  - R14's wait_flags gathers 32 flags at 128B stride -> every poll pulls 32
//    x 64B lines/WG; x128 WGs ~ 3 TB/s of flag-poll traffic at the coherence
//    point. Replace: arrival = ONE atomicAdd per WG to a per-group counter
//    (memory-side, pipelined); detect = all lanes poll ONE line (same-addr
//    loads merge). Poll traffic /32, detect ~ 1 RT.
//  - Same ordering as R14: h stores (relaxed agent) -> VMWAIT -> barrier ->
//    arrival add. Monotone counter targets = 32 x R14's flag targets.
//  - Everything else byte-identical to R14: 4 groups x 16 batches, 32 WGs/
//    group h-sliced (16 dims/WG, 1 gate/wave), f16-only h exchange (W hi+lo
//    Ootomo), coalesced conflict-free STAGE_H, x-part(t+1) pipelined over
//    the store-ack, sc0|sc1 coherence path (bit-exact family).
//  - Multiplexing abandoned (R10/R15/R16 all regressed): phases serialize
//    through the WG's own barrier chain; single-chain per WG is best.
#define NGROUP 4
#define WPG    32
#define NWG    128
#define BPG    16
#define HH  512
#define TT  64
#define VV  64
#define FF  128
#define SS  1024

typedef _Float16 f16;
typedef _Float16 f16x8 __attribute__((ext_vector_type(8)));
typedef float    f32x4 __attribute__((ext_vector_type(4)));
typedef unsigned int u32;
typedef unsigned short u16;
typedef u32 u32x4 __attribute__((ext_vector_type(4)));
typedef unsigned long long u64;

#define C1 4.8828125e-4f          // 2^-11
#define C2 2.384185791015625e-7f  // 2^-22

__device__ __forceinline__ void split8(const float* __restrict__ p, f16x8& hi, f16x8& lo) {
  f32x4 u = *(const f32x4*)p;
  f32x4 v = *(const f32x4*)(p + 4);
#pragma unroll
  for (int j = 0; j < 4; ++j) {
    f16 a = (f16)u[j]; hi[j]   = a; lo[j]   = (f16)((u[j] - (float)a) * 2048.0f);
    f16 b = (f16)v[j]; hi[4+j] = b; lo[4+j] = (f16)((v[j] - (float)b) * 2048.0f);
  }
}
__device__ __forceinline__ float sigmf_(float x) { return 1.0f / (1.0f + expf(-x)); }

// far (coherence-point) accessors — R8/R13/R14-proven pattern
__device__ __forceinline__ f32x4 ld16f(const void* p) {
  f32x4 r;
  asm volatile("global_load_dwordx4 %0, %1, off sc0 sc1" : "=v"(r) : "v"(p) : "memory");
  return r;
}
__device__ __forceinline__ void st4f(u32* p, u32 v) {
  __hip_atomic_store(p, v, __ATOMIC_RELAXED, __HIP_MEMORY_SCOPE_AGENT);
}
__device__ __forceinline__ void st4ff(float* p, float v) {
  __hip_atomic_store(p, v, __ATOMIC_RELAXED, __HIP_MEMORY_SCOPE_AGENT);
}
__device__ __forceinline__ u32 ld4f(const u32* p) {
  return __hip_atomic_load(p, __ATOMIC_RELAXED, __HIP_MEMORY_SCOPE_AGENT);
}
__device__ __forceinline__ void arrive(u32* p) {
  __hip_atomic_fetch_add(p, 1u, __ATOMIC_RELAXED, __HIP_MEMORY_SCOPE_AGENT);
}
#define VMWAIT asm volatile("s_waitcnt vmcnt(0)" ::: "memory")

// barrier detect: poll ONE counter line (all lanes same addr -> HW-merged)
__device__ __forceinline__ void wait_cnt(const u32* cnt, u32 target) {
  while (ld4f(cnt) < target)
    __builtin_amdgcn_s_sleep(1);
}

#define MFMA(d, a, b) d = __builtin_amdgcn_mfma_f32_16x16x32_f16(a, b, d, 0, 0, 0)

// one-shot h stage: group tile [16][256] u32 (f16 dim pairs) -> LDS f16.
// Thread (r=tid>>4, cq=tid&15), chunk u2: u32 cols cq*4+u2*64 of row r.
// Per instruction: 16 same-row lanes contiguous 256B (coalesced far reads);
// LDS write u32x4 at (r*1024 + cq*16 + u2*256) ^ ((r&7)<<4): conflict-free.
// rule #18: tie values through volatile asm + sched_barrier after VMWAIT.
#define STAGE_H(src_)                                                         \
  { const u32* src = (src_) + (size_t)(tid >> 4) * 256;                       \
    const int cq_ = tid & 15;                                                 \
    f32x4 sv[4];                                                              \
    _Pragma("unroll") for (int u2 = 0; u2 < 4; ++u2)                          \
      sv[u2] = ld16f(src + cq_*4 + u2*64);                                    \
    VMWAIT;                                                                   \
    _Pragma("unroll") for (int u2 = 0; u2 < 4; ++u2)                          \
      asm volatile("" : "+v"(sv[u2]));                                        \
    __builtin_amdgcn_sched_barrier(0);                                        \
    const int r_ = tid >> 4;                                                  \
    const size_t swz = (size_t)((r_ & 7) << 4);                               \
    _Pragma("unroll") for (int u2 = 0; u2 < 4; ++u2) {                        \
      size_t off = ((size_t)r_*1024 + (size_t)cq_*16 + (size_t)u2*256) ^ swz; \
      *(u32x4*)((char*)sh_h + off) = __builtin_bit_cast(u32x4, sv[u2]);       \
    } }                                                                       \
  __syncthreads();

// A-fragment read (row = batch mn, k-slice s), same swizzle as write side
#define LDA(s, ah)                                                            \
  { size_t o_ = ((size_t)mn * 1024 + (size_t)(s) * 64 + (size_t)(q8 * 2))     \
                ^ (size_t)((mn & 7) << 4);                                    \
    ah = *(const f16x8*)((const char*)sh_h + o_); }

// h-part: h f16-only; W hi+lo -> gates pick up C1-scaled W-lo correction.
#define HPART()                                                               \
  _Pragma("unroll") for (int s = 0; s < 16; ++s) {                            \
    f16x8 ah; LDA(s, ah);                                                     \
    MFMA(acc0, ah, whh_h[s]);                                                 \
    MFMA(acc1, ah, whh_l[s]);                                                 \
  }

// x-part for sig row ts (full Ootomo), (re)initializes acc0..2
#define XPART(ts)                                                             \
  { acc0 = zero4; acc1 = zero4; acc2 = zero4;                                 \
    const float* sb = sig + (size_t)(gb + mn) * (SS * FF) + (size_t)(ts) * FF;\
    _Pragma("unroll") for (int s = 0; s < 4; ++s) {                           \
      f16x8 xh, xl;                                                           \
      split8(sb + s * 32 + q8, xh, xl);                                       \
      MFMA(acc0, xh, wih_h[s]);                                               \
      MFMA(acc1, xl, wih_h[s]);                                               \
      MFMA(acc1, xh, wih_l[s]);                                               \
      MFMA(acc2, xl, wih_l[s]);                                               \
    } }

// C/D layout: col = lane&15 = h-dim, row = (lane>>4)*4 + r = batch
#define GWRITE()                                                              \
  _Pragma("unroll") for (int r = 0; r < 4; ++r)                               \
    gate_buf[w][q * 4 + r][mn] = acc0[r] + C1 * acc1[r] + C2 * acc2[r];

// pack h f16 pair across (even,odd) lanes via shfl; even tids store u32.
// h16 row = 256 u32: col = dim/2 = p*8 + ck/2.
#define HSTORE(dst)                                                           \
  { f16 hh = (f16)h;                                                          \
    u32 mine = (u32)__builtin_bit_cast(u16, hh);                              \
    u32 part = (u32)__shfl_xor((int)mine, 1, 64);                             \
    if ((tid & 1) == 0)                                                       \
      st4f((dst) + (size_t)cb * 256 + p * 8 + (ck >> 1), mine | (part << 16)); }

__global__ void __launch_bounds__(256, 1) lstm_seq2seq(
    const float* __restrict__ sig,   // [B,S,F]
    const int*   __restrict__ tgt,   // [B,T]
    const float* __restrict__ eWih,  // [2048,128]
    const float* __restrict__ eWhh,  // [2048,512]
    const float* __restrict__ eBih,  // [2048]
    const float* __restrict__ eBhh,  // [2048]
    const float* __restrict__ dWih,  // [2048,64]
    const float* __restrict__ dWhh,  // [2048,512]
    const float* __restrict__ dBih,  // [2048]
    const float* __restrict__ dBhh,  // [2048]
    const float* __restrict__ oW,    // [64,512]
    const float* __restrict__ oB,    // [64]
    float*       __restrict__ out,   // [B,T,V]
    unsigned char* __restrict__ ws)
{
  // ws layout (bytes): [0,512) counters: 4 groups x u32 at 128B stride;
  // [16384,16640) idxbuf u32[64]; [20480,151552) h16 4 groups x 2 buf x 16KB
  // u32 {f16 dim2j | f16 dim2j+1 <<16}; [151552,282624) hfg 4 groups x 32KB.
  // Zeroed region = [0,151552) every launch (ws re-poisoned 0xAA); packed 0
  // = h0 = zeros. hfg fully written before read (counter-guarded).
  const int wg = blockIdx.x;
  const int g  = wg >> 5;            // batch group
  const int p  = wg & 31;            // h-dim slice [p*16, p*16+16) per gate
  const int gb = g * BPG;            // global batch base
  u32* cnt    = (u32*)ws + (size_t)g * 32;   // one line per group
  u32* idxbuf = (u32*)(ws + 16384);
  u32* h16[2] = { (u32*)(ws + 20480) + (size_t)(g*2 + 0) * 4096,
                  (u32*)(ws + 20480) + (size_t)(g*2 + 1) * 4096 };
  float* hfg  = (float*)(ws + 151552) + (size_t)g * 8192;

  const int tid  = threadIdx.x;
  const int w    = tid >> 6;         // wave = gate (i,f,g,o)
  const int lane = tid & 63;
  const int q    = lane >> 4;
  const int mn   = lane & 15;
  const int q8   = q * 8;
  const int row  = w * HH + p * 16 + mn;  // weight row for this lane's B-frag
  const int cb   = tid >> 4;         // cell: local batch 0..15
  const int ck   = tid & 15;         // cell: dim within slice
  const int crow = p * 16 + ck;      // cell: h-dim

  __shared__ __attribute__((aligned(16))) f16 sh_h[16 * 512]; // 16KB swizzled
  __shared__ float gate_buf[4][16][17];
  __shared__ float bias_buf[4][16];
  __shared__ __attribute__((aligned(16))) float hrow[512];
  __shared__ double psum[64];

  // ---- weights: W_hh and W_ih hi/lo fragments in registers ----
  f16x8 whh_h[16], whh_l[16], wih_h[4], wih_l[4];
#pragma unroll
  for (int s = 0; s < 16; ++s)
    split8(eWhh + (size_t)row * HH + s * 32 + q8, whh_h[s], whh_l[s]);
#pragma unroll
  for (int s = 0; s < 4; ++s)
    split8(eWih + (size_t)row * FF + s * 32 + q8, wih_h[s], wih_l[s]);
  if (tid < 64) {
    int g4 = tid >> 4, kl = tid & 15;
    int r = g4 * HH + p * 16 + kl;
    bias_buf[g4][kl] = eBih[r] + eBhh[r];
  }
  if (p == 0 && tid < BPG)
    st4f(idxbuf + gb + tid, (u32)tgt[(size_t)(gb + tid) * TT]);  // target[:,0]
  __syncthreads();

  float c_reg = 0.f;
  int cur = 0;                       // h dbuf (zeroed by memset = h0)
  const f32x4 zero4 = {0.f, 0.f, 0.f, 0.f};
  f32x4 acc0, acc1, acc2;

  // ================= encoder: 1024 steps (x-part pipelined) =================
  XPART(0)
  for (int t = 0; t < SS; ++t) {
    wait_cnt(cnt, 32u * (u32)t);
    STAGE_H(h16[cur])
    HPART()
    GWRITE()
    __syncthreads();
    // LSTM cell: 1 h-value per thread (f32, precise libm)
    {
      float gi = gate_buf[0][cb][ck] + bias_buf[0][ck];
      float gf = gate_buf[1][cb][ck] + bias_buf[1][ck];
      float gg = gate_buf[2][cb][ck] + bias_buf[2][ck];
      float go = gate_buf[3][cb][ck] + bias_buf[3][ck];
      float c  = sigmf_(gf) * c_reg + sigmf_(gi) * tanhf(gg);
      float h  = sigmf_(go) * tanhf(c);
      c_reg = c;
      HSTORE(h16[cur ^ 1])
    }
    // x-part(t+1) overlaps the h-store ack (clamped: t=SS-1 result unused)
    XPART(t + 1 < SS ? t + 1 : SS - 1)
    VMWAIT;             // h store acked at coherence point (+ sig drained)
    __syncthreads();
    if (tid == 0) arrive(cnt);       // -> 32*(t+1) when all WGs done
    cur ^= 1;
  }

  // ================= decoder setup =================
#pragma unroll
  for (int s = 0; s < 16; ++s)
    split8(dWhh + (size_t)row * HH + s * 32 + q8, whh_h[s], whh_l[s]);
  __syncthreads();
  if (tid < 64) {
    int g4 = tid >> 4, kl = tid & 15;
    int r = g4 * HH + p * 16 + kl;
    bias_buf[g4][kl] = dBih[r] + dBhh[r];
  }
  __syncthreads();

  // ================= decoder: 64 steps =================
  for (int t = 0; t < TT; ++t) {
    // ---- phase A: cell. x = one_hot(idx) -> column gather at cell stage ----
    wait_cnt(cnt, 32u * (u32)(SS + 2 * t));
    acc0 = zero4; acc1 = zero4; acc2 = zero4;
    STAGE_H(h16[cur])
    HPART()
    GWRITE()
    __syncthreads();
    {
      int ib = (int)ld4f(idxbuf + gb + cb);
      float gi = gate_buf[0][cb][ck] + bias_buf[0][ck] + dWih[(size_t)(0*HH + crow) * VV + ib];
      float gf = gate_buf[1][cb][ck] + bias_buf[1][ck] + dWih[(size_t)(1*HH + crow) * VV + ib];
      float gg = gate_buf[2][cb][ck] + bias_buf[2][ck] + dWih[(size_t)(2*HH + crow) * VV + ib];
      float go = gate_buf[3][cb][ck] + bias_buf[3][ck] + dWih[(size_t)(3*HH + crow) * VV + ib];
      float c  = sigmf_(gf) * c_reg + sigmf_(gi) * tanhf(gg);
      float h  = sigmf_(go) * tanhf(c);
      c_reg = c;
      HSTORE(h16[cur ^ 1])
      st4ff(hfg + (size_t)cb * HH + crow, h);
    }
    VMWAIT;
    __syncthreads();
    if (tid == 0) arrive(cnt);       // -> 32*(SS+2t+1)
    int nxt = cur ^ 1;

    // ---- phase B: f64 logits + log_softmax + argmax (WG p<16 = batch p) ----
    wait_cnt(cnt, 32u * (u32)(SS + 2 * t + 1));
    if (p < BPG) {
      if (tid < 128) {
        f32x4 hv = ld16f(hfg + (size_t)p * HH + tid * 4);
        VMWAIT;
        *(f32x4*)&hrow[tid * 4] = hv;
      }
      __syncthreads();
      double acc = 0.0;
      if (w < 2) {                   // waves 0,1 split K=512 in halves
        const float* wr = oW + (size_t)lane * HH + w * 256;
        const float* hr = hrow + w * 256;
#pragma unroll 4
        for (int kc = 0; kc < 64; ++kc) {
          f32x4 hv = *(const f32x4*)(hr + kc * 4);
          f32x4 wv = *(const f32x4*)(wr + kc * 4);
          acc += (double)hv[0]*(double)wv[0] + (double)hv[1]*(double)wv[1]
               + (double)hv[2]*(double)wv[2] + (double)hv[3]*(double)wv[3];
        }
        if (w == 1) psum[lane] = acc;
      }
      __syncthreads();
      if (w == 0) {
        double l = acc + psum[lane] + (double)oB[lane];
        double mx = l; int ai = lane;
#pragma unroll
        for (int o = 32; o > 0; o >>= 1) {
          double om = __shfl_xor(mx, o, 64);
          int    oi = __shfl_xor(ai, o, 64);
          if (om > mx || (om == mx && oi < ai)) { mx = om; ai = oi; }
        }
        double se = exp(l - mx);
#pragma unroll
        for (int o = 32; o > 0; o >>= 1) se += __shfl_xor(se, o, 64);
        double lse = mx + log(se);
        out[((size_t)(gb + p) * TT + t) * VV + lane] = (float)(l - lse);
        if (lane == 0) st4f(idxbuf + gb + p, (u32)ai);
      }
    }
    VMWAIT;
    __syncthreads();
    if (tid == 0) arrive(cnt);       // -> 32*(SS+2t+2)
    cur = nxt;
  }
}

extern "C" void kernel_launch(void* const* d_in, const int* in_sizes, int n_in,
                              void* d_out, int out_size, void* d_ws, size_t ws_size,
                              hipStream_t stream) {
  (void)in_sizes; (void)n_in; (void)out_size; (void)ws_size;
  // zero: counters + idxbuf + h16 dbufs (ws re-poisoned 0xAA before every
  // timed launch -> must zero every call). hfg fully written before read.
  hipMemsetAsync(d_ws, 0, 151552, stream);
  lstm_seq2seq<<<dim3(NWG), dim3(256), 0, stream>>>(
      (const float*)d_in[0],  (const int*)d_in[1],
      (const float*)d_in[2],  (const float*)d_in[3],
      (const float*)d_in[4],  (const float*)d_in[5],
      (const float*)d_in[6],  (const float*)d_in[7],
      (const float*)d_in[8],  (const float*)d_in[9],
      (const float*)d_in[10], (const float*)d_in[11],
      (float*)d_out, (unsigned char*)d_ws);
}

// Round 12
// 5803.897 us; speedup vs baseline: 1.1713x; 1.0213x over previous
//
#include <hip/hip_runtime.h>
#include <cstddef>
#include <math.h>

// Problem: B=64, S=1024, F=128, H=512, V=64, T=64. f32 in/out.
// R18 = R14 (proven 5015us) with the flag protocol replaced by tag-in-data:
//  - h element = u64 {u32 packed 2xf16 dims, u32 step tag}, ONE relaxed agent
//    atomic store (fire-and-forget: no VMWAIT ack, no flag store, no arrive).
//    Consumer staging loads double as the readiness detector: issued
//    speculatively after the cell, covered by XPART, checked via tags,
//    stale 16B chunks re-issued. Chain: 4 coherence trips -> ~1-2.
//  - Overwrite-safety induction (R9-proven, bit-exact): store of h(t+3) into
//    buf[(t+1)&1] only happens after that WG staged h(t+2), which implies
//    every WG staged h(t+1) -> no consumer still needs the overwritten data.
//  - Encoder: NO flags/counters/barrier convoy at all (tag-gated free-run).
//    Decoder: idx + hfg also tagged u64 (R9 pattern). 2 barriers/step.
//  - R12 lesson kept: __syncthreads between encoder loop and decoder setup
//    (bias_buf overwrite vs last cell's reads).
//  - Everything else R14-identical: 4 groups x 16 batches, 32 WGs/group
//    h-sliced (16 dims/WG, 1 gate/wave), f16-only h (W Ootomo hi+lo),
//    coalesced stage loads, conflict-free swizzled LDS, sc0|sc1 path.
#define NGROUP 4
#define WPG    32
#define NWG    128
#define BPG    16
#define HH  512
#define TT  64
#define VV  64
#define FF  128
#define SS  1024

typedef _Float16 f16;
typedef _Float16 f16x8 __attribute__((ext_vector_type(8)));
typedef float    f32x4 __attribute__((ext_vector_type(4)));
typedef unsigned int u32;
typedef unsigned short u16;
typedef u32 u32x2 __attribute__((ext_vector_type(2)));
typedef unsigned long long u64;

#define C1 4.8828125e-4f          // 2^-11
#define C2 2.384185791015625e-7f  // 2^-22

__device__ __forceinline__ void split8(const float* __restrict__ p, f16x8& hi, f16x8& lo) {
  f32x4 u = *(const f32x4*)p;
  f32x4 v = *(const f32x4*)(p + 4);
#pragma unroll
  for (int j = 0; j < 4; ++j) {
    f16 a = (f16)u[j]; hi[j]   = a; lo[j]   = (f16)((u[j] - (float)a) * 2048.0f);
    f16 b = (f16)v[j]; hi[4+j] = b; lo[4+j] = (f16)((v[j] - (float)b) * 2048.0f);
  }
}
__device__ __forceinline__ float sigmf_(float x) { return 1.0f / (1.0f + expf(-x)); }

// far (coherence-point) accessors — proven sc0|sc1 family
__device__ __forceinline__ f32x4 ld16f(const void* p) {
  f32x4 r;
  asm volatile("global_load_dwordx4 %0, %1, off sc0 sc1" : "=v"(r) : "v"(p) : "memory");
  return r;
}
__device__ __forceinline__ u64 ld8f(const u64* p) {
  u64 r;
  asm volatile("global_load_dwordx2 %0, %1, off sc0 sc1" : "=v"(r) : "v"(p) : "memory");
  return r;
}
__device__ __forceinline__ void st8f(u64* p, u64 v) {
  __hip_atomic_store(p, v, __ATOMIC_RELAXED, __HIP_MEMORY_SCOPE_AGENT);
}
#define VMWAIT asm volatile("s_waitcnt vmcnt(0)" ::: "memory")

#define MFMA(d, a, b) d = __builtin_amdgcn_mfma_f32_16x16x32_f16(a, b, d, 0, 0, 0)

// ---- tagged h stage: group tile [16][256] u64 {2 dims, tag} -> LDS f16 ----
// Thread (r=tid>>4, cq=tid&15), chunk u2 (0..7): u64 idx cq*2 + u2*32 of row
// r -> 16 same-row lanes contiguous 256B per instruction (coalesced).
#define STAGE_ISSUE(src_)                                                     \
  _Pragma("unroll") for (int u2 = 0; u2 < 8; ++u2)                            \
    sv[u2] = ld16f((src_) + (size_t)(tid >> 4) * 256                          \
                   + (size_t)((tid & 15) * 2 + u2 * 32));

// rule #18: after VMWAIT tie results through volatile asm + sched_barrier so
// the register-only tag check can't be hoisted above the wait.
#define STAGE_WAIT(src_, tg)                                                  \
  for (;;) {                                                                  \
    VMWAIT;                                                                   \
    _Pragma("unroll") for (int u2 = 0; u2 < 8; ++u2)                          \
      asm volatile("" : "+v"(sv[u2]));                                        \
    __builtin_amdgcn_sched_barrier(0);                                        \
    u32 badv[8]; u32 anyb = 0;                                                \
    _Pragma("unroll") for (int u2 = 0; u2 < 8; ++u2) {                        \
      union { f32x4 f; u32 u4[4]; } U; U.f = sv[u2];                          \
      badv[u2] = (U.u4[1] ^ (u32)(tg)) | (U.u4[3] ^ (u32)(tg));               \
      anyb |= badv[u2];                                                       \
    }                                                                         \
    if (__all(anyb == 0)) break;                                              \
    __builtin_amdgcn_s_sleep(1);                                              \
    _Pragma("unroll") for (int u2 = 0; u2 < 8; ++u2)                          \
      if (badv[u2])                                                           \
        sv[u2] = ld16f((src_) + (size_t)(tid >> 4) * 256                      \
                       + (size_t)((tid & 15) * 2 + u2 * 32));                 \
  }

// unpack + swizzled LDS write: chunk u2 = dims [cq*4+u2*64 .. +4) of row r,
// u32x2 {pair0, pair1} at (r*1024 + cq*8 + u2*128) ^ ((r&7)<<4). Same
// conflict-free pattern as R13/R14.
#define STAGE_WRITE()                                                         \
  { const int r_ = tid >> 4, cq_ = tid & 15;                                  \
    const size_t swz = (size_t)((r_ & 7) << 4);                               \
    _Pragma("unroll") for (int u2 = 0; u2 < 8; ++u2) {                        \
      union { f32x4 f; u32 u4[4]; } U; U.f = sv[u2];                          \
      size_t off = ((size_t)r_*1024 + (size_t)cq_*8 + (size_t)u2*128) ^ swz;  \
      *(u32x2*)((char*)sh_h + off) = (u32x2){U.u4[0], U.u4[2]};               \
    } }                                                                       \
  __syncthreads();

// A-fragment read (row = batch mn, k-slice s), same swizzle as write side
#define LDA(s, ah)                                                            \
  { size_t o_ = ((size_t)mn * 1024 + (size_t)(s) * 64 + (size_t)(q8 * 2))     \
                ^ (size_t)((mn & 7) << 4);                                    \
    ah = *(const f16x8*)((const char*)sh_h + o_); }

// h-part: h f16-only; W hi+lo
#define HPART()                                                               \
  _Pragma("unroll") for (int s = 0; s < 16; ++s) {                            \
    f16x8 ah; LDA(s, ah);                                                     \
    MFMA(acc0, ah, whh_h[s]);                                                 \
    MFMA(acc1, ah, whh_l[s]);                                                 \
  }

// x-part for sig row ts (full Ootomo), (re)initializes acc0..2
#define XPART(ts)                                                             \
  { acc0 = zero4; acc1 = zero4; acc2 = zero4;                                 \
    const float* sb = sig + (size_t)(gb + mn) * (SS * FF) + (size_t)(ts) * FF;\
    _Pragma("unroll") for (int s = 0; s < 4; ++s) {                           \
      f16x8 xh, xl;                                                           \
      split8(sb + s * 32 + q8, xh, xl);                                       \
      MFMA(acc0, xh, wih_h[s]);                                               \
      MFMA(acc1, xl, wih_h[s]);                                               \
      MFMA(acc1, xh, wih_l[s]);                                               \
      MFMA(acc2, xl, wih_l[s]);                                               \
    } }

// C/D layout: col = lane&15 = h-dim, row = (lane>>4)*4 + r = batch
#define GWRITE()                                                              \
  _Pragma("unroll") for (int r = 0; r < 4; ++r)                               \
    gate_buf[w][q * 4 + r][mn] = acc0[r] + C1 * acc1[r] + C2 * acc2[r];

// pack h f16 pair across (even,odd) lanes via shfl; even tid stores tagged
// u64 {pair, tag} at row cb, u64 col p*8 + ck/2. Fire-and-forget.
#define HSTORE64(dst, tg)                                                     \
  { u32 mine = (u32)__builtin_bit_cast(u16, (f16)h);                          \
    u32 part = (u32)__shfl_xor((int)mine, 1, 64);                             \
    if ((tid & 1) == 0)                                                       \
      st8f((dst) + (size_t)cb * 256 + p * 8 + (ck >> 1),                      \
           (u64)(mine | (part << 16)) | ((u64)(u32)(tg) << 32)); }

__global__ void __launch_bounds__(256, 1) lstm_seq2seq(
    const float* __restrict__ sig,   // [B,S,F]
    const int*   __restrict__ tgt,   // [B,T]
    const float* __restrict__ eWih,  // [2048,128]
    const float* __restrict__ eWhh,  // [2048,512]
    const float* __restrict__ eBih,  // [2048]
    const float* __restrict__ eBhh,  // [2048]
    const float* __restrict__ dWih,  // [2048,64]
    const float* __restrict__ dWhh,  // [2048,512]
    const float* __restrict__ dBih,  // [2048]
    const float* __restrict__ dBhh,  // [2048]
    const float* __restrict__ oW,    // [64,512]
    const float* __restrict__ oB,    // [64]
    float*       __restrict__ out,   // [B,T,V]
    unsigned char* __restrict__ ws)
{
  // ws layout (bytes): [0,512) idx64 u64[64] {idx, tag};
  // [4096,266240) h16 4 groups x 2 bufs x [16][256] u64 {2xf16 dims, tag};
  // [266240,528384) hfg 4 groups x [16][512] u64 {f32 h, tag}.
  // Zeroed every launch (ws re-poisoned 0xAA): h16 tag0+zeros = h0 state;
  // idx/hfg tags must differ from all expected tags (0 does).
  u64* idx64 = (u64*)ws;
  u64* h16[2] = { (u64*)(ws + 4096) + (size_t)((blockIdx.x >> 5)*2 + 0) * 4096,
                  (u64*)(ws + 4096) + (size_t)((blockIdx.x >> 5)*2 + 1) * 4096 };
  u64* hfg   = (u64*)(ws + 266240) + (size_t)(blockIdx.x >> 5) * 8192;

  const int wg = blockIdx.x;
  const int g  = wg >> 5;            // batch group
  const int p  = wg & 31;            // h-dim slice [p*16, p*16+16) per gate
  const int gb = g * BPG;            // global batch base

  const int tid  = threadIdx.x;
  const int w    = tid >> 6;         // wave = gate (i,f,g,o)
  const int lane = tid & 63;
  const int q    = lane >> 4;
  const int mn   = lane & 15;
  const int q8   = q * 8;
  const int row  = w * HH + p * 16 + mn;  // weight row for this lane's B-frag
  const int cb   = tid >> 4;         // cell: local batch 0..15
  const int ck   = tid & 15;         // cell: dim within slice
  const int crow = p * 16 + ck;      // cell: h-dim

  __shared__ __attribute__((aligned(16))) f16 sh_h[16 * 512]; // 16KB swizzled
  __shared__ float gate_buf[4][16][17];
  __shared__ float bias_buf[4][16];
  __shared__ __attribute__((aligned(16))) float hrow[512];
  __shared__ double psum[64];

  // ---- weights: W_hh and W_ih hi/lo fragments in registers ----
  f16x8 whh_h[16], whh_l[16], wih_h[4], wih_l[4];
#pragma unroll
  for (int s = 0; s < 16; ++s)
    split8(eWhh + (size_t)row * HH + s * 32 + q8, whh_h[s], whh_l[s]);
#pragma unroll
  for (int s = 0; s < 4; ++s)
    split8(eWih + (size_t)row * FF + s * 32 + q8, wih_h[s], wih_l[s]);
  if (tid < 64) {
    int g4 = tid >> 4, kl = tid & 15;
    int r = g4 * HH + p * 16 + kl;
    bias_buf[g4][kl] = eBih[r] + eBhh[r];
  }
  if (p == 0 && tid < BPG)           // initial idx = target[:,0], tag 1
    st8f(idx64 + gb + tid,
         (u64)(u32)tgt[(size_t)(gb + tid) * TT] | (1ull << 32));
  __syncthreads();

  float c_reg = 0.f;
  const f32x4 zero4 = {0.f, 0.f, 0.f, 0.f};
  f32x4 acc0, acc1, acc2;
  f32x4 sv[8];

  // ================= encoder: 1024 steps, tag-gated free-run ==============
  STAGE_ISSUE(h16[0])                // h0: zeros, tag 0 (memset) — hits
  XPART(0)
  for (int t = 0; t < SS; ++t) {
    STAGE_WAIT(h16[t & 1], t)
    STAGE_WRITE()                    // + barrier
    HPART()
    GWRITE()
    __syncthreads();
    // LSTM cell: 1 h-value per thread (f32, precise libm)
    {
      float gi = gate_buf[0][cb][ck] + bias_buf[0][ck];
      float gf = gate_buf[1][cb][ck] + bias_buf[1][ck];
      float gg = gate_buf[2][cb][ck] + bias_buf[2][ck];
      float go = gate_buf[3][cb][ck] + bias_buf[3][ck];
      float c  = sigmf_(gf) * c_reg + sigmf_(gi) * tanhf(gg);
      float h  = sigmf_(go) * tanhf(c);
      c_reg = c;
      HSTORE64(h16[(t + 1) & 1], t + 1)          // fire-and-forget
    }
    STAGE_ISSUE(h16[(t + 1) & 1])    // speculative loads for t+1
    XPART(t + 1 < SS ? t + 1 : SS - 1)           // covers load RT
  }

  // R12 lesson: fence last cell's bias_buf/gate_buf reads vs setup writes
  __syncthreads();

  // ================= decoder setup =================
#pragma unroll
  for (int s = 0; s < 16; ++s)
    split8(dWhh + (size_t)row * HH + s * 32 + q8, whh_h[s], whh_l[s]);
  if (tid < 64) {
    int g4 = tid >> 4, kl = tid & 15;
    int r = g4 * HH + p * 16 + kl;
    bias_buf[g4][kl] = dBih[r] + dBhh[r];
  }
  __syncthreads();

  // ================= decoder: 64 steps =================
  for (int t = 0; t < TT; ++t) {
    // ---- phase A: cell. x = one_hot(idx) -> column gather at cell stage ----
    STAGE_ISSUE(h16[(SS + t) & 1])
    const u64* iap = idx64 + gb + cb;
    u64 iv = ld8f(iap);
    acc0 = zero4; acc1 = zero4; acc2 = zero4;
    STAGE_WAIT(h16[(SS + t) & 1], SS + t)
    STAGE_WRITE()
    HPART()
    GWRITE()
    __syncthreads();
    {
      for (;;) {                     // poll idx {argmax(t-1) or initial}, tag t+1
        asm volatile("" : "+v"(iv));
        __builtin_amdgcn_sched_barrier(0);
        if ((u32)(iv >> 32) == (u32)(t + 1)) break;
        __builtin_amdgcn_s_sleep(1);
        iv = ld8f(iap);
        VMWAIT;
      }
      int ib = (int)(u32)iv;
      float gi = gate_buf[0][cb][ck] + bias_buf[0][ck] + dWih[(size_t)(0*HH + crow) * VV + ib];
      float gf = gate_buf[1][cb][ck] + bias_buf[1][ck] + dWih[(size_t)(1*HH + crow) * VV + ib];
      float gg = gate_buf[2][cb][ck] + bias_buf[2][ck] + dWih[(size_t)(2*HH + crow) * VV + ib];
      float go = gate_buf[3][cb][ck] + bias_buf[3][ck] + dWih[(size_t)(3*HH + crow) * VV + ib];
      float c  = sigmf_(gf) * c_reg + sigmf_(gi) * tanhf(gg);
      float h  = sigmf_(go) * tanhf(c);
      c_reg = c;
      HSTORE64(h16[(SS + t + 1) & 1], SS + t + 1)
      st8f(hfg + (size_t)cb * HH + crow,
           (u64)__builtin_bit_cast(u32, h) | ((u64)(u32)(SS + t + 1) << 32));
    }

    // ---- phase B: f64 logits + log_softmax + argmax (WG p<16 = batch p) ----
    if (p < BPG) {
      const u32 tg = (u32)(SS + t + 1);
      if (tid < 128) {               // stage batch p's h row (tagged poll)
        const u64* hp = hfg + (size_t)p * HH + (size_t)tid * 4;
        f32x4 a = ld16f(hp), b2 = ld16f(hp + 2);
        for (;;) {
          VMWAIT;
          asm volatile("" : "+v"(a), "+v"(b2));
          __builtin_amdgcn_sched_barrier(0);
          union { f32x4 f; u32 u4[4]; } A, B2; A.f = a; B2.f = b2;
          u32 bad = (A.u4[1]^tg) | (A.u4[3]^tg) | (B2.u4[1]^tg) | (B2.u4[3]^tg);
          if (__all(bad == 0)) break;
          __builtin_amdgcn_s_sleep(1);
          a = ld16f(hp); b2 = ld16f(hp + 2);
        }
        union { f32x4 f; u32 u4[4]; } A, B2; A.f = a; B2.f = b2;
        hrow[tid*4+0] = __builtin_bit_cast(float, A.u4[0]);
        hrow[tid*4+1] = __builtin_bit_cast(float, A.u4[2]);
        hrow[tid*4+2] = __builtin_bit_cast(float, B2.u4[0]);
        hrow[tid*4+3] = __builtin_bit_cast(float, B2.u4[2]);
      }
      __syncthreads();
      double acc = 0.0;
      if (w < 2) {                   // waves 0,1 split K=512 in halves
        const float* wr = oW + (size_t)lane * HH + w * 256;
        const float* hr = hrow + w * 256;
#pragma unroll 4
        for (int kc = 0; kc < 64; ++kc) {
          f32x4 hv = *(const f32x4*)(hr + kc * 4);
          f32x4 wv = *(const f32x4*)(wr + kc * 4);
          acc += (double)hv[0]*(double)wv[0] + (double)hv[1]*(double)wv[1]
               + (double)hv[2]*(double)wv[2] + (double)hv[3]*(double)wv[3];
        }
        if (w == 1) psum[lane] = acc;
      }
      __syncthreads();
      if (w == 0) {
        double l = acc + psum[lane] + (double)oB[lane];
        double mx = l; int ai = lane;
#pragma unroll
        for (int o = 32; o > 0; o >>= 1) {
          double om = __shfl_xor(mx, o, 64);
          int    oi = __shfl_xor(ai, o, 64);
          if (om > mx || (om == mx && oi < ai)) { mx = om; ai = oi; }
        }
        double se = exp(l - mx);
#pragma unroll
        for (int o = 32; o > 0; o >>= 1) se += __shfl_xor(se, o, 64);
        double lse = mx + log(se);
        out[((size_t)(gb + p) * TT + t) * VV + lane] = (float)(l - lse);
        if (lane == 0)               // argmax -> idx for step t+1, tag t+2
          st8f(idx64 + gb + p, (u64)(u32)ai | ((u64)(u32)(t + 2) << 32));
      }
    }
    __syncthreads();                 // hrow/psum/gate_buf reuse fence
  }
}

extern "C" void kernel_launch(void* const* d_in, const int* in_sizes, int n_in,
                              void* d_out, int out_size, void* d_ws, size_t ws_size,
                              hipStream_t stream) {
  (void)in_sizes; (void)n_in; (void)out_size; (void)ws_size;
  // zero: idx64 + h16 + hfg (h16 tag0+zeros IS the initial h0; all other
  // expected tags > 0). ws re-poisoned 0xAA before every timed launch.
  hipMemsetAsync(d_ws, 0, 528384, stream);
  lstm_seq2seq<<<dim3(NWG), dim3(256), 0, stream>>>(
      (const float*)d_in[0],  (const int*)d_in[1],
      (const float*)d_in[2],  (const float*)d_in[3],
      (const float*)d_in[4],  (const float*)d_in[5],
      (const float*)d_in[6],  (const float*)d_in[7],
      (const float*)d_in[8],  (const float*)d_in[9],
      (const float*)d_in[10], (const float*)d_in[11],
      (float*)d_out, (unsigned char*)d_ws);
}

// Round 13
// 5271.129 us; speedup vs baseline: 1.2897x; 1.1011x over previous
//
#include <hip/hip_runtime.h>
#include <cstddef>
#include <math.h>

// Problem: B=64, S=1024, F=128, H=512, V=64, T=64. f32 in/out.
// R19 = R14 (proven best, 5015us, absmax 0.031) + single-wave flag polling:
//  - Mechanism tally across R8-R18: flags(5015 best) < tags(5804) <
//    counter(5927) < multiplex(6108+) -> the flag protocol on the sc0|sc1
//    coherence path is the floor mechanism; remaining cost = 2 serial
//    coherence trips (detect+fetch) stretched by contention.
//  - Last lever: R14 polls flags with ALL 4 waves (4x redundant gather of the
//    hottest 32 lines in the system, continuously, per WG). Gate the poll to
//    wave 0 + __syncthreads: poll traffic /4, frees L3 ports for the very
//    producer stores being awaited.
//  - Everything else byte-identical to R14: 4 groups x 16 batches, 32 WGs/
//    group h-sliced (16 dims/WG, 1 gate/wave); f16-only h exchange (W_hh/
//    W_ih full Ootomo hi+lo); coalesced conflict-free STAGE_H; x-part(t+1)
//    pipelined over the h-store ack; 1 packed u32 h-store via shfl pair.
#define NGROUP 4
#define WPG    32
#define NWG    128
#define BPG    16
#define HH  512
#define TT  64
#define VV  64
#define FF  128
#define SS  1024

typedef _Float16 f16;
typedef _Float16 f16x8 __attribute__((ext_vector_type(8)));
typedef float    f32x4 __attribute__((ext_vector_type(4)));
typedef unsigned int u32;
typedef unsigned short u16;
typedef u32 u32x4 __attribute__((ext_vector_type(4)));
typedef unsigned long long u64;

#define C1 4.8828125e-4f          // 2^-11
#define C2 2.384185791015625e-7f  // 2^-22

__device__ __forceinline__ void split8(const float* __restrict__ p, f16x8& hi, f16x8& lo) {
  f32x4 u = *(const f32x4*)p;
  f32x4 v = *(const f32x4*)(p + 4);
#pragma unroll
  for (int j = 0; j < 4; ++j) {
    f16 a = (f16)u[j]; hi[j]   = a; lo[j]   = (f16)((u[j] - (float)a) * 2048.0f);
    f16 b = (f16)v[j]; hi[4+j] = b; lo[4+j] = (f16)((v[j] - (float)b) * 2048.0f);
  }
}
__device__ __forceinline__ float sigmf_(float x) { return 1.0f / (1.0f + expf(-x)); }

// far (coherence-point) accessors — R8/R13/R14-proven pattern
__device__ __forceinline__ f32x4 ld16f(const void* p) {
  f32x4 r;
  asm volatile("global_load_dwordx4 %0, %1, off sc0 sc1" : "=v"(r) : "v"(p) : "memory");
  return r;
}
__device__ __forceinline__ void st4f(u32* p, u32 v) {
  __hip_atomic_store(p, v, __ATOMIC_RELAXED, __HIP_MEMORY_SCOPE_AGENT);
}
__device__ __forceinline__ void st4ff(float* p, float v) {
  __hip_atomic_store(p, v, __ATOMIC_RELAXED, __HIP_MEMORY_SCOPE_AGENT);
}
__device__ __forceinline__ u32 ld4f(const u32* p) {
  return __hip_atomic_load(p, __ATOMIC_RELAXED, __HIP_MEMORY_SCOPE_AGENT);
}
#define VMWAIT asm volatile("s_waitcnt vmcnt(0)" ::: "memory")

// barrier detect: wave 0 only polls the group's 32 flags (128B stride);
// other waves wait at the following __syncthreads (poll traffic /4).
__device__ __forceinline__ void wait_flags(const u32* flags, u32 target, int lane) {
  const u32* a = flags + (size_t)(lane & 31) * 32;
  while (!__all(ld4f(a) >= target))
    __builtin_amdgcn_s_sleep(1);
}
#define WAITF(tg)                                                             \
  { if (w == 0) wait_flags(fl, (u32)(tg), lane);                              \
    __syncthreads(); }

#define MFMA(d, a, b) d = __builtin_amdgcn_mfma_f32_16x16x32_f16(a, b, d, 0, 0, 0)

// one-shot h stage: group tile [16][256] u32 (f16 dim pairs) -> LDS f16.
// Thread (r=tid>>4, cq=tid&15), chunk u2: u32 cols cq*4+u2*64 of row r.
// Per instruction: 16 same-row lanes contiguous 256B (coalesced far reads);
// LDS write u32x4 at (r*1024 + cq*16 + u2*256) ^ ((r&7)<<4): conflict-free.
// rule #18: tie values through volatile asm + sched_barrier after VMWAIT.
#define STAGE_H(src_)                                                         \
  { const u32* src = (src_) + (size_t)(tid >> 4) * 256;                       \
    const int cq_ = tid & 15;                                                 \
    f32x4 sv[4];                                                              \
    _Pragma("unroll") for (int u2 = 0; u2 < 4; ++u2)                          \
      sv[u2] = ld16f(src + cq_*4 + u2*64);                                    \
    VMWAIT;                                                                   \
    _Pragma("unroll") for (int u2 = 0; u2 < 4; ++u2)                          \
      asm volatile("" : "+v"(sv[u2]));                                        \
    __builtin_amdgcn_sched_barrier(0);                                        \
    const int r_ = tid >> 4;                                                  \
    const size_t swz = (size_t)((r_ & 7) << 4);                               \
    _Pragma("unroll") for (int u2 = 0; u2 < 4; ++u2) {                        \
      size_t off = ((size_t)r_*1024 + (size_t)cq_*16 + (size_t)u2*256) ^ swz; \
      *(u32x4*)((char*)sh_h + off) = __builtin_bit_cast(u32x4, sv[u2]);       \
    } }                                                                       \
  __syncthreads();

// A-fragment read (row = batch mn, k-slice s), same swizzle as write side
#define LDA(s, ah)                                                            \
  { size_t o_ = ((size_t)mn * 1024 + (size_t)(s) * 64 + (size_t)(q8 * 2))     \
                ^ (size_t)((mn & 7) << 4);                                    \
    ah = *(const f16x8*)((const char*)sh_h + o_); }

// h-part: h f16-only; W hi+lo -> gates pick up C1-scaled W-lo correction.
#define HPART()                                                               \
  _Pragma("unroll") for (int s = 0; s < 16; ++s) {                            \
    f16x8 ah; LDA(s, ah);                                                     \
    MFMA(acc0, ah, whh_h[s]);                                                 \
    MFMA(acc1, ah, whh_l[s]);                                                 \
  }

// x-part for sig row ts (full Ootomo), (re)initializes acc0..2
#define XPART(ts)                                                             \
  { acc0 = zero4; acc1 = zero4; acc2 = zero4;                                 \
    const float* sb = sig + (size_t)(gb + mn) * (SS * FF) + (size_t)(ts) * FF;\
    _Pragma("unroll") for (int s = 0; s < 4; ++s) {                           \
      f16x8 xh, xl;                                                           \
      split8(sb + s * 32 + q8, xh, xl);                                       \
      MFMA(acc0, xh, wih_h[s]);                                               \
      MFMA(acc1, xl, wih_h[s]);                                               \
      MFMA(acc1, xh, wih_l[s]);                                               \
      MFMA(acc2, xl, wih_l[s]);                                               \
    } }

// C/D layout: col = lane&15 = h-dim, row = (lane>>4)*4 + r = batch
#define GWRITE()                                                              \
  _Pragma("unroll") for (int r = 0; r < 4; ++r)                               \
    gate_buf[w][q * 4 + r][mn] = acc0[r] + C1 * acc1[r] + C2 * acc2[r];

// pack h f16 pair across (even,odd) lanes via shfl; even tids store u32.
// h16 row = 256 u32: col = dim/2 = p*8 + ck/2.
#define HSTORE(dst)                                                           \
  { f16 hh = (f16)h;                                                          \
    u32 mine = (u32)__builtin_bit_cast(u16, hh);                              \
    u32 part = (u32)__shfl_xor((int)mine, 1, 64);                             \
    if ((tid & 1) == 0)                                                       \
      st4f((dst) + (size_t)cb * 256 + p * 8 + (ck >> 1), mine | (part << 16)); }

__global__ void __launch_bounds__(256, 1) lstm_seq2seq(
    const float* __restrict__ sig,   // [B,S,F]
    const int*   __restrict__ tgt,   // [B,T]
    const float* __restrict__ eWih,  // [2048,128]
    const float* __restrict__ eWhh,  // [2048,512]
    const float* __restrict__ eBih,  // [2048]
    const float* __restrict__ eBhh,  // [2048]
    const float* __restrict__ dWih,  // [2048,64]
    const float* __restrict__ dWhh,  // [2048,512]
    const float* __restrict__ dBih,  // [2048]
    const float* __restrict__ dBhh,  // [2048]
    const float* __restrict__ oW,    // [64,512]
    const float* __restrict__ oB,    // [64]
    float*       __restrict__ out,   // [B,T,V]
    unsigned char* __restrict__ ws)
{
  // ws layout (bytes): [0,16384) flags 4 groups x 32 x 128B;
  // [16384,16640) idxbuf u32[64]; [20480,151552) h16 4 groups x 2 buf x 16KB
  // u32 {f16 dim2j | f16 dim2j+1 <<16}; [151552,282624) hfg 4 groups x 32KB.
  // Zeroed region = [0,151552) every launch (ws re-poisoned 0xAA); packed 0
  // = h0 = zeros. hfg fully written before read (flag-guarded).
  const int wg = blockIdx.x;
  const int g  = wg >> 5;            // batch group
  const int p  = wg & 31;            // h-dim slice [p*16, p*16+16) per gate
  const int gb = g * BPG;            // global batch base
  u32* fl     = (u32*)ws + (size_t)g * 1024;
  u32* idxbuf = (u32*)(ws + 16384);
  u32* h16[2] = { (u32*)(ws + 20480) + (size_t)(g*2 + 0) * 4096,
                  (u32*)(ws + 20480) + (size_t)(g*2 + 1) * 4096 };
  float* hfg  = (float*)(ws + 151552) + (size_t)g * 8192;

  const int tid  = threadIdx.x;
  const int w    = tid >> 6;         // wave = gate (i,f,g,o)
  const int lane = tid & 63;
  const int q    = lane >> 4;
  const int mn   = lane & 15;
  const int q8   = q * 8;
  const int row  = w * HH + p * 16 + mn;  // weight row for this lane's B-frag
  const int cb   = tid >> 4;         // cell: local batch 0..15
  const int ck   = tid & 15;         // cell: dim within slice
  const int crow = p * 16 + ck;      // cell: h-dim

  __shared__ __attribute__((aligned(16))) f16 sh_h[16 * 512]; // 16KB swizzled
  __shared__ float gate_buf[4][16][17];
  __shared__ float bias_buf[4][16];
  __shared__ __attribute__((aligned(16))) float hrow[512];
  __shared__ double psum[64];

  // ---- weights: W_hh and W_ih hi/lo fragments in registers ----
  f16x8 whh_h[16], whh_l[16], wih_h[4], wih_l[4];
#pragma unroll
  for (int s = 0; s < 16; ++s)
    split8(eWhh + (size_t)row * HH + s * 32 + q8, whh_h[s], whh_l[s]);
#pragma unroll
  for (int s = 0; s < 4; ++s)
    split8(eWih + (size_t)row * FF + s * 32 + q8, wih_h[s], wih_l[s]);
  if (tid < 64) {
    int g4 = tid >> 4, kl = tid & 15;
    int r = g4 * HH + p * 16 + kl;
    bias_buf[g4][kl] = eBih[r] + eBhh[r];
  }
  if (p == 0 && tid < BPG)
    st4f(idxbuf + gb + tid, (u32)tgt[(size_t)(gb + tid) * TT]);  // target[:,0]
  __syncthreads();

  float c_reg = 0.f;
  int cur = 0;                       // h dbuf (zeroed by memset = h0)
  const f32x4 zero4 = {0.f, 0.f, 0.f, 0.f};
  f32x4 acc0, acc1, acc2;

  // ================= encoder: 1024 steps (x-part pipelined) =================
  XPART(0)
  for (int t = 0; t < SS; ++t) {
    WAITF(t)
    STAGE_H(h16[cur])
    HPART()
    GWRITE()
    __syncthreads();
    // LSTM cell: 1 h-value per thread (f32, precise libm)
    {
      float gi = gate_buf[0][cb][ck] + bias_buf[0][ck];
      float gf = gate_buf[1][cb][ck] + bias_buf[1][ck];
      float gg = gate_buf[2][cb][ck] + bias_buf[2][ck];
      float go = gate_buf[3][cb][ck] + bias_buf[3][ck];
      float c  = sigmf_(gf) * c_reg + sigmf_(gi) * tanhf(gg);
      float h  = sigmf_(go) * tanhf(c);
      c_reg = c;
      HSTORE(h16[cur ^ 1])
    }
    // x-part(t+1) overlaps the h-store ack (clamped: t=SS-1 result unused)
    XPART(t + 1 < SS ? t + 1 : SS - 1)
    VMWAIT;             // h store acked at coherence point (+ sig drained)
    __syncthreads();
    if (tid == 0) st4f(fl + p * 32, (u32)(t + 1));
    cur ^= 1;
  }

  // ================= decoder setup =================
#pragma unroll
  for (int s = 0; s < 16; ++s)
    split8(dWhh + (size_t)row * HH + s * 32 + q8, whh_h[s], whh_l[s]);
  __syncthreads();
  if (tid < 64) {
    int g4 = tid >> 4, kl = tid & 15;
    int r = g4 * HH + p * 16 + kl;
    bias_buf[g4][kl] = dBih[r] + dBhh[r];
  }
  __syncthreads();

  // ================= decoder: 64 steps =================
  for (int t = 0; t < TT; ++t) {
    // ---- phase A: cell. x = one_hot(idx) -> column gather at cell stage ----
    WAITF(SS + 2 * t)
    acc0 = zero4; acc1 = zero4; acc2 = zero4;
    STAGE_H(h16[cur])
    HPART()
    GWRITE()
    __syncthreads();
    {
      int ib = (int)ld4f(idxbuf + gb + cb);
      float gi = gate_buf[0][cb][ck] + bias_buf[0][ck] + dWih[(size_t)(0*HH + crow) * VV + ib];
      float gf = gate_buf[1][cb][ck] + bias_buf[1][ck] + dWih[(size_t)(1*HH + crow) * VV + ib];
      float gg = gate_buf[2][cb][ck] + bias_buf[2][ck] + dWih[(size_t)(2*HH + crow) * VV + ib];
      float go = gate_buf[3][cb][ck] + bias_buf[3][ck] + dWih[(size_t)(3*HH + crow) * VV + ib];
      float c  = sigmf_(gf) * c_reg + sigmf_(gi) * tanhf(gg);
      float h  = sigmf_(go) * tanhf(c);
      c_reg = c;
      HSTORE(h16[cur ^ 1])
      st4ff(hfg + (size_t)cb * HH + crow, h);
    }
    VMWAIT;
    __syncthreads();
    if (tid == 0) st4f(fl + p * 32, (u32)(SS + 2 * t + 1));
    int nxt = cur ^ 1;

    // ---- phase B: f64 logits + log_softmax + argmax (WG p<16 = batch p) ----
    WAITF(SS + 2 * t + 1)
    if (p < BPG) {
      if (tid < 128) {
        f32x4 hv = ld16f(hfg + (size_t)p * HH + tid * 4);
        VMWAIT;
        *(f32x4*)&hrow[tid * 4] = hv;
      }
      __syncthreads();
      double acc = 0.0;
      if (w < 2) {                   // waves 0,1 split K=512 in halves
        const float* wr = oW + (size_t)lane * HH + w * 256;
        const float* hr = hrow + w * 256;
#pragma unroll 4
        for (int kc = 0; kc < 64; ++kc) {
          f32x4 hv = *(const f32x4*)(hr + kc * 4);
          f32x4 wv = *(const f32x4*)(wr + kc * 4);
          acc += (double)hv[0]*(double)wv[0] + (double)hv[1]*(double)wv[1]
               + (double)hv[2]*(double)wv[2] + (double)hv[3]*(double)wv[3];
        }
        if (w == 1) psum[lane] = acc;
      }
      __syncthreads();
      if (w == 0) {
        double l = acc + psum[lane] + (double)oB[lane];
        double mx = l; int ai = lane;
#pragma unroll
        for (int o = 32; o > 0; o >>= 1) {
          double om = __shfl_xor(mx, o, 64);
          int    oi = __shfl_xor(ai, o, 64);
          if (om > mx || (om == mx && oi < ai)) { mx = om; ai = oi; }
        }
        double se = exp(l - mx);
#pragma unroll
        for (int o = 32; o > 0; o >>= 1) se += __shfl_xor(se, o, 64);
        double lse = mx + log(se);
        out[((size_t)(gb + p) * TT + t) * VV + lane] = (float)(l - lse);
        if (lane == 0) st4f(idxbuf + gb + p, (u32)ai);
      }
    }
    VMWAIT;
    __syncthreads();
    if (tid == 0) st4f(fl + p * 32, (u32)(SS + 2 * t + 2));
    cur = nxt;
  }
}

extern "C" void kernel_launch(void* const* d_in, const int* in_sizes, int n_in,
                              void* d_out, int out_size, void* d_ws, size_t ws_size,
                              hipStream_t stream) {
  (void)in_sizes; (void)n_in; (void)out_size; (void)ws_size;
  // zero: flags + idxbuf + h16 dbufs (ws re-poisoned 0xAA before every timed
  // launch -> must zero every call). hfg fully written before read.
  hipMemsetAsync(d_ws, 0, 151552, stream);
  lstm_seq2seq<<<dim3(NWG), dim3(256), 0, stream>>>(
      (const float*)d_in[0],  (const int*)d_in[1],
      (const float*)d_in[2],  (const float*)d_in[3],
      (const float*)d_in[4],  (const float*)d_in[5],
      (const float*)d_in[6],  (const float*)d_in[7],
      (const float*)d_in[8],  (const float*)d_in[9],
      (const float*)d_in[10], (const float*)d_in[11],
      (float*)d_out, (unsigned char*)d_ws);
}

// Round 14
// 5008.546 us; speedup vs baseline: 1.3573x; 1.0524x over previous
//
#include <hip/hip_runtime.h>
#include <cstddef>
#include <math.h>

// Problem: B=64, S=1024, F=128, H=512, V=64, T=64. f32 in/out.
// R20 = R14 verbatim (session best: 5015us, absmax 0.031, Round-8-proven).
// Session conclusion: the kernel is communication-LATENCY-bound, not at a
// memory/compute roofline (HBM 1.4%, MFMA 3%, VALU 6%). The recurrence
// forces 1088 sequential global exchange rounds; each costs ~2 serial
// coherence-point round trips (producer h-store visibility -> consumer
// detect+fetch) ~ 3.5us under 128-WG load + ~0.8us compute. Measured
// mechanism space: flags-4wave(5015, best) < flags-1wave(5271) <
// tags(5804) < counter(5927) < multiplex(6108+); XCD-local L2 raced.
// Design (R14):
//  - 4 groups x 16 batches; 32 WGs/group h-sliced: 16 h-dims/WG, 1 gate/wave.
//  - W_hh/W_ih register-resident as Ootomo f16 hi+lo; h exchanged f16-only
//    (error budget ~6e-3 << 0.09 threshold; c_reg stays f32).
//  - Per step: wait flags -> one-shot coalesced h stage (sc0|sc1 far loads,
//    conflict-free swizzled LDS) -> 32 h-MFMAs -> gate LDS exchange -> cell
//    (1 h/thread, packed u32 store via shfl pair) -> XPART(t+1) overlaps the
//    store-ack -> VMWAIT -> barrier -> flag.
//  - Decoder: phase A cell with one-hot column gather, phase B f64 logits +
//    log_softmax + argmax feedback, flag-chained.
#define NGROUP 4
#define WPG    32
#define NWG    128
#define BPG    16
#define HH  512
#define TT  64
#define VV  64
#define FF  128
#define SS  1024

typedef _Float16 f16;
typedef _Float16 f16x8 __attribute__((ext_vector_type(8)));
typedef float    f32x4 __attribute__((ext_vector_type(4)));
typedef unsigned int u32;
typedef unsigned short u16;
typedef u32 u32x4 __attribute__((ext_vector_type(4)));
typedef unsigned long long u64;

#define C1 4.8828125e-4f          // 2^-11
#define C2 2.384185791015625e-7f  // 2^-22

__device__ __forceinline__ void split8(const float* __restrict__ p, f16x8& hi, f16x8& lo) {
  f32x4 u = *(const f32x4*)p;
  f32x4 v = *(const f32x4*)(p + 4);
#pragma unroll
  for (int j = 0; j < 4; ++j) {
    f16 a = (f16)u[j]; hi[j]   = a; lo[j]   = (f16)((u[j] - (float)a) * 2048.0f);
    f16 b = (f16)v[j]; hi[4+j] = b; lo[4+j] = (f16)((v[j] - (float)b) * 2048.0f);
  }
}
__device__ __forceinline__ float sigmf_(float x) { return 1.0f / (1.0f + expf(-x)); }

// far (coherence-point) accessors — R4/R8/R13/R14-proven pattern
__device__ __forceinline__ f32x4 ld16f(const void* p) {
  f32x4 r;
  asm volatile("global_load_dwordx4 %0, %1, off sc0 sc1" : "=v"(r) : "v"(p) : "memory");
  return r;
}
__device__ __forceinline__ void st4f(u32* p, u32 v) {
  __hip_atomic_store(p, v, __ATOMIC_RELAXED, __HIP_MEMORY_SCOPE_AGENT);
}
__device__ __forceinline__ void st4ff(float* p, float v) {
  __hip_atomic_store(p, v, __ATOMIC_RELAXED, __HIP_MEMORY_SCOPE_AGENT);
}
__device__ __forceinline__ u32 ld4f(const u32* p) {
  return __hip_atomic_load(p, __ATOMIC_RELAXED, __HIP_MEMORY_SCOPE_AGENT);
}
#define VMWAIT asm volatile("s_waitcnt vmcnt(0)" ::: "memory")

// barrier: poll this group's 32 per-WG flags with one 64-lane gather
__device__ __forceinline__ void wait_flags(const u32* flags, u32 target, int lane) {
  const u32* a = flags + (size_t)(lane & 31) * 32;   // 128B stride
  while (!__all(ld4f(a) >= target))
    __builtin_amdgcn_s_sleep(1);
}

#define MFMA(d, a, b) d = __builtin_amdgcn_mfma_f32_16x16x32_f16(a, b, d, 0, 0, 0)

// one-shot h stage: group tile [16][256] u32 (f16 dim pairs) -> LDS f16.
// Thread (r=tid>>4, cq=tid&15), chunk u2: u32 cols cq*4+u2*64 of row r.
// Per instruction: 16 same-row lanes contiguous 256B (coalesced far reads);
// LDS write u32x4 at (r*1024 + cq*16 + u2*256) ^ ((r&7)<<4): conflict-free.
// rule #18: tie values through volatile asm + sched_barrier after VMWAIT.
#define STAGE_H(src_)                                                         \
  { const u32* src = (src_) + (size_t)(tid >> 4) * 256;                       \
    const int cq_ = tid & 15;                                                 \
    f32x4 sv[4];                                                              \
    _Pragma("unroll") for (int u2 = 0; u2 < 4; ++u2)                          \
      sv[u2] = ld16f(src + cq_*4 + u2*64);                                    \
    VMWAIT;                                                                   \
    _Pragma("unroll") for (int u2 = 0; u2 < 4; ++u2)                          \
      asm volatile("" : "+v"(sv[u2]));                                        \
    __builtin_amdgcn_sched_barrier(0);                                        \
    const int r_ = tid >> 4;                                                  \
    const size_t swz = (size_t)((r_ & 7) << 4);                               \
    _Pragma("unroll") for (int u2 = 0; u2 < 4; ++u2) {                        \
      size_t off = ((size_t)r_*1024 + (size_t)cq_*16 + (size_t)u2*256) ^ swz; \
      *(u32x4*)((char*)sh_h + off) = __builtin_bit_cast(u32x4, sv[u2]);       \
    } }                                                                       \
  __syncthreads();

// A-fragment read (row = batch mn, k-slice s), same swizzle as write side
#define LDA(s, ah)                                                            \
  { size_t o_ = ((size_t)mn * 1024 + (size_t)(s) * 64 + (size_t)(q8 * 2))     \
                ^ (size_t)((mn & 7) << 4);                                    \
    ah = *(const f16x8*)((const char*)sh_h + o_); }

// h-part: h f16-only; W hi+lo -> gates pick up C1-scaled W-lo correction.
#define HPART()                                                               \
  _Pragma("unroll") for (int s = 0; s < 16; ++s) {                            \
    f16x8 ah; LDA(s, ah);                                                     \
    MFMA(acc0, ah, whh_h[s]);                                                 \
    MFMA(acc1, ah, whh_l[s]);                                                 \
  }

// x-part for sig row ts (full Ootomo), (re)initializes acc0..2
#define XPART(ts)                                                             \
  { acc0 = zero4; acc1 = zero4; acc2 = zero4;                                 \
    const float* sb = sig + (size_t)(gb + mn) * (SS * FF) + (size_t)(ts) * FF;\
    _Pragma("unroll") for (int s = 0; s < 4; ++s) {                           \
      f16x8 xh, xl;                                                           \
      split8(sb + s * 32 + q8, xh, xl);                                       \
      MFMA(acc0, xh, wih_h[s]);                                               \
      MFMA(acc1, xl, wih_h[s]);                                               \
      MFMA(acc1, xh, wih_l[s]);                                               \
      MFMA(acc2, xl, wih_l[s]);                                               \
    } }

// C/D layout: col = lane&15 = h-dim, row = (lane>>4)*4 + r = batch
#define GWRITE()                                                              \
  _Pragma("unroll") for (int r = 0; r < 4; ++r)                               \
    gate_buf[w][q * 4 + r][mn] = acc0[r] + C1 * acc1[r] + C2 * acc2[r];

// pack h f16 pair across (even,odd) lanes via shfl; even tids store u32.
// h16 row = 256 u32: col = dim/2 = p*8 + ck/2.
#define HSTORE(dst)                                                           \
  { f16 hh = (f16)h;                                                          \
    u32 mine = (u32)__builtin_bit_cast(u16, hh);                              \
    u32 part = (u32)__shfl_xor((int)mine, 1, 64);                             \
    if ((tid & 1) == 0)                                                       \
      st4f((dst) + (size_t)cb * 256 + p * 8 + (ck >> 1), mine | (part << 16)); }

__global__ void __launch_bounds__(256, 1) lstm_seq2seq(
    const float* __restrict__ sig,   // [B,S,F]
    const int*   __restrict__ tgt,   // [B,T]
    const float* __restrict__ eWih,  // [2048,128]
    const float* __restrict__ eWhh,  // [2048,512]
    const float* __restrict__ eBih,  // [2048]
    const float* __restrict__ eBhh,  // [2048]
    const float* __restrict__ dWih,  // [2048,64]
    const float* __restrict__ dWhh,  // [2048,512]
    const float* __restrict__ dBih,  // [2048]
    const float* __restrict__ dBhh,  // [2048]
    const float* __restrict__ oW,    // [64,512]
    const float* __restrict__ oB,    // [64]
    float*       __restrict__ out,   // [B,T,V]
    unsigned char* __restrict__ ws)
{
  // ws layout (bytes): [0,16384) flags 4 groups x 32 x 128B;
  // [16384,16640) idxbuf u32[64]; [20480,151552) h16 4 groups x 2 buf x 16KB
  // u32 {f16 dim2j | f16 dim2j+1 <<16}; [151552,282624) hfg 4 groups x 32KB.
  // Zeroed region = [0,151552) every launch (ws re-poisoned 0xAA); packed 0
  // = h0 = zeros. hfg fully written before read (flag-guarded).
  const int wg = blockIdx.x;
  const int g  = wg >> 5;            // batch group
  const int p  = wg & 31;            // h-dim slice [p*16, p*16+16) per gate
  const int gb = g * BPG;            // global batch base
  u32* fl     = (u32*)ws + (size_t)g * 1024;
  u32* idxbuf = (u32*)(ws + 16384);
  u32* h16[2] = { (u32*)(ws + 20480) + (size_t)(g*2 + 0) * 4096,
                  (u32*)(ws + 20480) + (size_t)(g*2 + 1) * 4096 };
  float* hfg  = (float*)(ws + 151552) + (size_t)g * 8192;

  const int tid  = threadIdx.x;
  const int w    = tid >> 6;         // wave = gate (i,f,g,o)
  const int lane = tid & 63;
  const int q    = lane >> 4;
  const int mn   = lane & 15;
  const int q8   = q * 8;
  const int row  = w * HH + p * 16 + mn;  // weight row for this lane's B-frag
  const int cb   = tid >> 4;         // cell: local batch 0..15
  const int ck   = tid & 15;         // cell: dim within slice
  const int crow = p * 16 + ck;      // cell: h-dim

  __shared__ __attribute__((aligned(16))) f16 sh_h[16 * 512]; // 16KB swizzled
  __shared__ float gate_buf[4][16][17];
  __shared__ float bias_buf[4][16];
  __shared__ __attribute__((aligned(16))) float hrow[512];
  __shared__ double psum[64];

  // ---- weights: W_hh and W_ih hi/lo fragments in registers ----
  f16x8 whh_h[16], whh_l[16], wih_h[4], wih_l[4];
#pragma unroll
  for (int s = 0; s < 16; ++s)
    split8(eWhh + (size_t)row * HH + s * 32 + q8, whh_h[s], whh_l[s]);
#pragma unroll
  for (int s = 0; s < 4; ++s)
    split8(eWih + (size_t)row * FF + s * 32 + q8, wih_h[s], wih_l[s]);
  if (tid < 64) {
    int g4 = tid >> 4, kl = tid & 15;
    int r = g4 * HH + p * 16 + kl;
    bias_buf[g4][kl] = eBih[r] + eBhh[r];
  }
  if (p == 0 && tid < BPG)
    st4f(idxbuf + gb + tid, (u32)tgt[(size_t)(gb + tid) * TT]);  // target[:,0]
  __syncthreads();

  float c_reg = 0.f;
  int cur = 0;                       // h dbuf (zeroed by memset = h0)
  const f32x4 zero4 = {0.f, 0.f, 0.f, 0.f};
  f32x4 acc0, acc1, acc2;

  // ================= encoder: 1024 steps (x-part pipelined) =================
  XPART(0)
  for (int t = 0; t < SS; ++t) {
    wait_flags(fl, (u32)t, lane);
    STAGE_H(h16[cur])
    HPART()
    GWRITE()
    __syncthreads();
    // LSTM cell: 1 h-value per thread (f32, precise libm)
    {
      float gi = gate_buf[0][cb][ck] + bias_buf[0][ck];
      float gf = gate_buf[1][cb][ck] + bias_buf[1][ck];
      float gg = gate_buf[2][cb][ck] + bias_buf[2][ck];
      float go = gate_buf[3][cb][ck] + bias_buf[3][ck];
      float c  = sigmf_(gf) * c_reg + sigmf_(gi) * tanhf(gg);
      float h  = sigmf_(go) * tanhf(c);
      c_reg = c;
      HSTORE(h16[cur ^ 1])
    }
    // x-part(t+1) overlaps the h-store ack (clamped: t=SS-1 result unused)
    XPART(t + 1 < SS ? t + 1 : SS - 1)
    VMWAIT;             // h store acked at coherence point (+ sig drained)
    __syncthreads();
    if (tid == 0) st4f(fl + p * 32, (u32)(t + 1));
    cur ^= 1;
  }

  // ================= decoder setup =================
#pragma unroll
  for (int s = 0; s < 16; ++s)
    split8(dWhh + (size_t)row * HH + s * 32 + q8, whh_h[s], whh_l[s]);
  __syncthreads();
  if (tid < 64) {
    int g4 = tid >> 4, kl = tid & 15;
    int r = g4 * HH + p * 16 + kl;
    bias_buf[g4][kl] = dBih[r] + dBhh[r];
  }
  __syncthreads();

  // ================= decoder: 64 steps =================
  for (int t = 0; t < TT; ++t) {
    // ---- phase A: cell. x = one_hot(idx) -> column gather at cell stage ----
    wait_flags(fl, (u32)(SS + 2 * t), lane);
    acc0 = zero4; acc1 = zero4; acc2 = zero4;
    STAGE_H(h16[cur])
    HPART()
    GWRITE()
    __syncthreads();
    {
      int ib = (int)ld4f(idxbuf + gb + cb);
      float gi = gate_buf[0][cb][ck] + bias_buf[0][ck] + dWih[(size_t)(0*HH + crow) * VV + ib];
      float gf = gate_buf[1][cb][ck] + bias_buf[1][ck] + dWih[(size_t)(1*HH + crow) * VV + ib];
      float gg = gate_buf[2][cb][ck] + bias_buf[2][ck] + dWih[(size_t)(2*HH + crow) * VV + ib];
      float go = gate_buf[3][cb][ck] + bias_buf[3][ck] + dWih[(size_t)(3*HH + crow) * VV + ib];
      float c  = sigmf_(gf) * c_reg + sigmf_(gi) * tanhf(gg);
      float h  = sigmf_(go) * tanhf(c);
      c_reg = c;
      HSTORE(h16[cur ^ 1])
      st4ff(hfg + (size_t)cb * HH + crow, h);
    }
    VMWAIT;
    __syncthreads();
    if (tid == 0) st4f(fl + p * 32, (u32)(SS + 2 * t + 1));
    int nxt = cur ^ 1;

    // ---- phase B: f64 logits + log_softmax + argmax (WG p<16 = batch p) ----
    wait_flags(fl, (u32)(SS + 2 * t + 1), lane);
    if (p < BPG) {
      if (tid < 128) {
        f32x4 hv = ld16f(hfg + (size_t)p * HH + tid * 4);
        VMWAIT;
        *(f32x4*)&hrow[tid * 4] = hv;
      }
      __syncthreads();
      double acc = 0.0;
      if (w < 2) {                   // waves 0,1 split K=512 in halves
        const float* wr = oW + (size_t)lane * HH + w * 256;
        const float* hr = hrow + w * 256;
#pragma unroll 4
        for (int kc = 0; kc < 64; ++kc) {
          f32x4 hv = *(const f32x4*)(hr + kc * 4);
          f32x4 wv = *(const f32x4*)(wr + kc * 4);
          acc += (double)hv[0]*(double)wv[0] + (double)hv[1]*(double)wv[1]
               + (double)hv[2]*(double)wv[2] + (double)hv[3]*(double)wv[3];
        }
        if (w == 1) psum[lane] = acc;
      }
      __syncthreads();
      if (w == 0) {
        double l = acc + psum[lane] + (double)oB[lane];
        double mx = l; int ai = lane;
#pragma unroll
        for (int o = 32; o > 0; o >>= 1) {
          double om = __shfl_xor(mx, o, 64);
          int    oi = __shfl_xor(ai, o, 64);
          if (om > mx || (om == mx && oi < ai)) { mx = om; ai = oi; }
        }
        double se = exp(l - mx);
#pragma unroll
        for (int o = 32; o > 0; o >>= 1) se += __shfl_xor(se, o, 64);
        double lse = mx + log(se);
        out[((size_t)(gb + p) * TT + t) * VV + lane] = (float)(l - lse);
        if (lane == 0) st4f(idxbuf + gb + p, (u32)ai);
      }
    }
    VMWAIT;
    __syncthreads();
    if (tid == 0) st4f(fl + p * 32, (u32)(SS + 2 * t + 2));
    cur = nxt;
  }
}

extern "C" void kernel_launch(void* const* d_in, const int* in_sizes, int n_in,
                              void* d_out, int out_size, void* d_ws, size_t ws_size,
                              hipStream_t stream) {
  (void)in_sizes; (void)n_in; (void)out_size; (void)ws_size;
  // zero: flags + idxbuf + h16 dbufs (ws re-poisoned 0xAA before every timed
  // launch -> must zero every call). hfg fully written before read.
  hipMemsetAsync(d_ws, 0, 151552, stream);
  lstm_seq2seq<<<dim3(NWG), dim3(256), 0, stream>>>(
      (const float*)d_in[0],  (const int*)d_in[1],
      (const float*)d_in[2],  (const float*)d_in[3],
      (const float*)d_in[4],  (const float*)d_in[5],
      (const float*)d_in[6],  (const float*)d_in[7],
      (const float*)d_in[8],  (const float*)d_in[9],
      (const float*)d_in[10], (const float*)d_in[11],
      (float*)d_out, (unsigned char*)d_ws);
}